// Round 6
// baseline (413.260 us; speedup 1.0000x reference)
//
#include <hip/hip_runtime.h>

// FFJORD CNF on MI355X. Transposed-MFMA design: every layer computed as
// H^T = W^T · X^T with v_mfma_f32_16x16x16_f16. For K=16 the C/D fragment
// layout (col=lane&15=sample, row=(lane>>4)*4+reg=feature) equals the
// B-operand layout, so layer outputs feed the next layer with only in-lane
// tanh + f32->f16 converts. Time column folded into bias: b_eff = b + t*W_row.
//
// R5: sched_barrier(0) between feature blocks killed the scratch traffic
// (4.6 GB -> 34 MB, dur 1277 -> 402 us, VGPR 68). Now pipe-overlap-bound:
// MfmaUtil 50 / VALUBusy 58 at 31% occupancy (2.5 waves/SIMD; LDS-limited
// 3 blocks/CU @ 256 thr). R6: block=1024 (16 waves) at same LDS/block ->
// 2 blocks/CU x 16 waves = 32 waves/CU, 8/SIMD - waves cover each other's
// MFMA<->VALU phase transitions.

typedef _Float16 h4 __attribute__((ext_vector_type(4)));
typedef float f4 __attribute__((ext_vector_type(4)));

#define MFMA16(A, B, C) __builtin_amdgcn_mfma_f32_16x16x16f16((A), (B), (C), 0, 0, 0)
#define SB() __builtin_amdgcn_sched_barrier(0)

__device__ __forceinline__ float fast_tanh(float x) {
  float e = __expf(2.0f * x);
  return 1.0f - 2.0f * __builtin_amdgcn_rcpf(e + 1.0f);
}

// ---------------- prepack: global weights -> MFMA fragment order in ws ----
// ws layout (bytes):
//   [0      .. 8192 )  w0 frags: 16 fragchunks x 64 lanes x h4   (8 KB)
//   [8192   .. 40960)  w1 frags: 64 fragchunks x 64 lanes x h4   (32 KB)
//   [40960  .. 49152)  w2 frags: 16 fragchunks x 64 lanes x h4   (8 KB)
//   [49152  .. 51456)  bias/time-row floats: bw[576]
//       bw[0:128]=b0  bw[128:256]=W0row32  bw[256:384]=b1 bw[384:512]=W1row128
//       bw[512:544]=b2 bw[544:576]=W2row128
__global__ void prepack_kernel(const float* __restrict__ W0, const float* __restrict__ b0,
                               const float* __restrict__ W1, const float* __restrict__ b1,
                               const float* __restrict__ W2, const float* __restrict__ b2,
                               char* __restrict__ ws) {
  h4* w0f = (h4*)(ws);
  h4* w1f = (h4*)(ws + 8192);
  h4* w2f = (h4*)(ws + 40960);
  float* bw = (float*)(ws + 49152);
  int tid = blockIdx.x * blockDim.x + threadIdx.x;
  int np = gridDim.x * blockDim.x;
  // A-fragment: A[m=f*16+(lane&15)][k=c*16+(lane>>4)*4+j] = W^T[m][k] = W[k][m]
  for (int e = tid; e < 1024; e += np) {
    int fc = e >> 6, lane = e & 63;
    int row = (fc >> 1) * 16 + (lane & 15);   // output feature (0..127)
    int kb = (fc & 1) * 16 + ((lane >> 4) << 2);
    h4 v;
#pragma unroll
    for (int j = 0; j < 4; j++) v[j] = (_Float16)W0[(kb + j) * 128 + row];
    w0f[e] = v;
  }
  for (int e = tid; e < 4096; e += np) {
    int fc = e >> 6, lane = e & 63;
    int row = (fc >> 3) * 16 + (lane & 15);
    int kb = (fc & 7) * 16 + ((lane >> 4) << 2);
    h4 v;
#pragma unroll
    for (int j = 0; j < 4; j++) v[j] = (_Float16)W1[(kb + j) * 128 + row];
    w1f[e] = v;
  }
  for (int e = tid; e < 1024; e += np) {
    int fc = e >> 6, lane = e & 63;
    int row = (fc >> 3) * 16 + (lane & 15);   // output feature (0..31)
    int kb = (fc & 7) * 16 + ((lane >> 4) << 2);
    h4 v;
#pragma unroll
    for (int j = 0; j < 4; j++) v[j] = (_Float16)W2[(kb + j) * 32 + row];
    w2f[e] = v;
  }
  for (int e = tid; e < 128; e += np) {
    bw[e] = b0[e];
    bw[128 + e] = W0[32 * 128 + e];
    bw[256 + e] = b1[e];
    bw[384 + e] = W1[128 * 128 + e];
  }
  for (int e = tid; e < 32; e += np) {
    bw[512 + e] = b2[e];
    bw[544 + e] = W2[128 * 32 + e];
  }
}

// ---- per-layer macros: all state in NAMED registers, offsets constant ----
#define TANHPACK(ap, at, HH, HD)                                              \
  {                                                                           \
    float th0 = fast_tanh((ap).x), th1 = fast_tanh((ap).y);                   \
    float th2 = fast_tanh((ap).z), th3 = fast_tanh((ap).w);                   \
    HH = (h4){(_Float16)th0, (_Float16)th1, (_Float16)th2, (_Float16)th3};    \
    HD = (h4){(_Float16)((1.0f - th0 * th0) * (at).x),                        \
              (_Float16)((1.0f - th1 * th1) * (at).y),                        \
              (_Float16)((1.0f - th2 * th2) * (at).z),                        \
              (_Float16)((1.0f - th3 * th3) * (at).w)};                       \
  }

#define L1(F, HH, HD)                                                         \
  {                                                                           \
    f4 bb = *(const f4*)&s_bw[(F) * 16 + g4];                                 \
    f4 bt = *(const f4*)&s_bw[128 + (F) * 16 + g4];                           \
    f4 ap = bb + t * bt;                                                      \
    f4 at = {0.0f, 0.0f, 0.0f, 0.0f};                                         \
    h4 A0 = s_w0[((F) * 2 + 0) * 64 + lane];                                  \
    h4 A1 = s_w0[((F) * 2 + 1) * 64 + lane];                                  \
    ap = MFMA16(A0, hz0, ap);                                                 \
    ap = MFMA16(A1, hz1, ap);                                                 \
    at = MFMA16(A0, hE0, at);                                                 \
    at = MFMA16(A1, hE1, at);                                                 \
    TANHPACK(ap, at, HH, HD)                                                  \
  }                                                                           \
  SB();

#define L2T(F, C, HHc, HDc)                                                   \
  {                                                                           \
    h4 A = s_w1[((F) * 8 + (C)) * 64 + lane];                                 \
    ap = MFMA16(A, HHc, ap);                                                  \
    at = MFMA16(A, HDc, at);                                                  \
  }

#define L2(F, GG, GD)                                                         \
  {                                                                           \
    f4 bb = *(const f4*)&s_bw[256 + (F) * 16 + g4];                           \
    f4 bt = *(const f4*)&s_bw[384 + (F) * 16 + g4];                           \
    f4 ap = bb + t * bt;                                                      \
    f4 at = {0.0f, 0.0f, 0.0f, 0.0f};                                         \
    L2T(F, 0, hh0, hd0) L2T(F, 1, hh1, hd1) L2T(F, 2, hh2, hd2)               \
    L2T(F, 3, hh3, hd3) L2T(F, 4, hh4, hd4) L2T(F, 5, hh5, hd5)               \
    L2T(F, 6, hh6, hd6) L2T(F, 7, hh7, hd7)                                   \
    TANHPACK(ap, at, GG, GD)                                                  \
  }                                                                           \
  SB();

#define L3T(F, C, GGc, GDc)                                                   \
  {                                                                           \
    h4 A = s_w2[((F) * 8 + (C)) * 64 + lane];                                 \
    ap = MFMA16(A, GGc, ap);                                                  \
    at = MFMA16(A, GDc, at);                                                  \
  }

#define L3(F, KC, EH)                                                         \
  {                                                                           \
    f4 bb = *(const f4*)&s_bw[512 + (F) * 16 + g4];                           \
    f4 bt = *(const f4*)&s_bw[544 + (F) * 16 + g4];                           \
    f4 ap = bb + t * bt;                                                      \
    f4 at = {0.0f, 0.0f, 0.0f, 0.0f};                                         \
    L3T(F, 0, g10, gd0) L3T(F, 1, g11, gd1) L3T(F, 2, g12, gd2)               \
    L3T(F, 3, g13, gd3) L3T(F, 4, g14, gd4) L3T(F, 5, g15, gd5)               \
    L3T(F, 6, g16, gd6) L3T(F, 7, g17, gd7)                                   \
    KC = ap;                                                                  \
    lp += (EH).x * at.x + (EH).y * at.y + (EH).z * at.z + (EH).w * at.w;      \
  }                                                                           \
  SB();

// ------------- main kernel: 16 samples/wave, 16 waves/block ---------------
__global__ __launch_bounds__(1024, 2) void ffjord_kernel(
    const float* __restrict__ z1g, const float* __restrict__ epsg,
    const char* __restrict__ ws, float* __restrict__ out) {
  __shared__ h4 s_w0[1024];   // 8 KB
  __shared__ h4 s_w1[4096];   // 32 KB
  __shared__ h4 s_w2[1024];   // 8 KB
  __shared__ float s_bw[576]; // 2.25 KB

  {
    int tt = threadIdx.x;
    const f4* s0 = (const f4*)(ws);
    const f4* s1 = (const f4*)(ws + 8192);
    const f4* s2 = (const f4*)(ws + 40960);
    const f4* s3 = (const f4*)(ws + 49152);
    f4* d0 = (f4*)s_w0;
    f4* d1 = (f4*)s_w1;
    f4* d2 = (f4*)s_w2;
    f4* d3 = (f4*)s_bw;
    if (tt < 512) d0[tt] = s0[tt];
#pragma unroll
    for (int i = 0; i < 2; i++) d1[tt + 1024 * i] = s1[tt + 1024 * i];
    if (tt < 512) d2[tt] = s2[tt];
    if (tt < 144) d3[tt] = s3[tt];
  }
  __syncthreads();

  const int lane = threadIdx.x & 63;
  const int wv = threadIdx.x >> 6;
  const int sl = lane & 15;
  const int g4 = ((lane >> 4) << 2);
  const int sample = (blockIdx.x * 16 + wv) * 16 + sl;

  // per-lane state: features {c*16 + g4 + j}, c in {0,1}, j in 0..3
  f4 za, zb, ea, eb;
  {
    const f4* zp = (const f4*)(z1g + sample * 32);
    za = zp[g4 >> 2];
    zb = zp[(16 + g4) >> 2];
    const f4* ep = (const f4*)(epsg + sample * 32);
    ea = ep[g4 >> 2];
    eb = ep[(16 + g4) >> 2];
  }
  const h4 hE0 = {(_Float16)ea.x, (_Float16)ea.y, (_Float16)ea.z, (_Float16)ea.w};
  const h4 hE1 = {(_Float16)eb.x, (_Float16)eb.y, (_Float16)eb.z, (_Float16)eb.w};

  float ld = 0.0f;

  // RK4, reversed time: 5 steps, dt = -0.2
#pragma unroll 1
  for (int step = 0; step < 5; step++) {
    float t1 = 1.0f - 0.2f * (float)step;
    f4 kca = {0.0f, 0.0f, 0.0f, 0.0f}, kcb = {0.0f, 0.0f, 0.0f, 0.0f};
    f4 dka = {0.0f, 0.0f, 0.0f, 0.0f}, dkb = {0.0f, 0.0f, 0.0f, 0.0f};
    float dl = 0.0f;
#pragma unroll 1
    for (int st = 0; st < 4; st++) {
      // stage input scale == stage t offset: {0, -0.1, -0.1, -0.2}
      float isc = (st == 0) ? 0.0f : ((st == 3) ? -0.2f : -0.1f);
      float wg = (st == 1 || st == 2) ? 2.0f : 1.0f;
      float t = t1 + isc;
      h4 hz0 = {(_Float16)(za.x + isc * kca.x), (_Float16)(za.y + isc * kca.y),
                (_Float16)(za.z + isc * kca.z), (_Float16)(za.w + isc * kca.w)};
      h4 hz1 = {(_Float16)(zb.x + isc * kcb.x), (_Float16)(zb.y + isc * kcb.y),
                (_Float16)(zb.z + isc * kcb.z), (_Float16)(zb.w + isc * kcb.w)};
      SB();

      // layer 1 (32 -> 128, tanh), primal + tangent
      h4 hh0, hh1, hh2, hh3, hh4, hh5, hh6, hh7;
      h4 hd0, hd1, hd2, hd3, hd4, hd5, hd6, hd7;
      L1(0, hh0, hd0) L1(1, hh1, hd1) L1(2, hh2, hd2) L1(3, hh3, hd3)
      L1(4, hh4, hd4) L1(5, hh5, hd5) L1(6, hh6, hd6) L1(7, hh7, hd7)

      // layer 2 (128 -> 128, tanh)
      h4 g10, g11, g12, g13, g14, g15, g16, g17;
      h4 gd0, gd1, gd2, gd3, gd4, gd5, gd6, gd7;
      L2(0, g10, gd0) L2(1, g11, gd1) L2(2, g12, gd2) L2(3, g13, gd3)
      L2(4, g14, gd4) L2(5, g15, gd5) L2(6, g16, gd6) L2(7, g17, gd7)

      // layer 3 (128 -> 32, linear) + Hutchinson partial
      float lp = 0.0f;
      L3(0, kca, ea)
      L3(1, kcb, eb)
      lp += __shfl_xor(lp, 16, 64);
      lp += __shfl_xor(lp, 32, 64);

      dka += wg * kca;
      dkb += wg * kcb;
      dl += wg * lp;
    }
    za += (-0.2f / 6.0f) * dka;
    zb += (-0.2f / 6.0f) * dkb;
    ld += (0.2f / 6.0f) * dl;   // ld -= dlogpz, dlogpz = dl*(dt/6), dt=-0.2
  }

  {
    f4* op = (f4*)(out + sample * 32);
    op[g4 >> 2] = za;
    op[(16 + g4) >> 2] = zb;
    if (lane < 16) out[131072 * 32 + sample] = ld;
  }
}

extern "C" void kernel_launch(void* const* d_in, const int* in_sizes, int n_in,
                              void* d_out, int out_size, void* d_ws, size_t ws_size,
                              hipStream_t stream) {
  (void)in_sizes; (void)n_in; (void)out_size; (void)ws_size;
  const float* z1 = (const float*)d_in[0];
  const float* eps = (const float*)d_in[1];
  const float* W0 = (const float*)d_in[2];
  const float* b0 = (const float*)d_in[3];
  const float* W1 = (const float*)d_in[4];
  const float* b1 = (const float*)d_in[5];
  const float* W2 = (const float*)d_in[6];
  const float* b2 = (const float*)d_in[7];
  float* out = (float*)d_out;

  prepack_kernel<<<16, 256, 0, stream>>>(W0, b0, W1, b1, W2, b2, (char*)d_ws);
  ffjord_kernel<<<131072 / 256, 1024, 0, stream>>>(z1, eps, (const char*)d_ws, out);
}

// Round 8
// 332.338 us; speedup vs baseline: 1.2435x; 1.2435x over previous
//
#include <hip/hip_runtime.h>

// FFJORD CNF on MI355X. Transposed-MFMA design: every layer computed as
// H^T = W^T · X^T. R7: all MFMAs switched to the NATIVE gfx950 shape
// v_mfma_f32_16x16x32_f16 (K=32). Counter history showed VALUBusy includes
// MFMA (ratio locked at 1.15x across all rounds) -> kernel was MFMA-issue
// bound at ~50% on the legacy 16x16x16 shape (~15cy/instr effective).
// K=32 halves MFMA count: L1 16, L2 64, L3 16 = 96/eval (was 192).
// Chain trick: K=32 B-fragment = two stacked K=16 fragments, so
// B8 = cat(frag(2c), frag(2c+1)); A-prepack uses the same slot->k map as
// the B chain, which is sufficient for correctness regardless of the HW's
// internal k permutation (A/B layouts are symmetric, labels cancel).

typedef _Float16 h4 __attribute__((ext_vector_type(4)));
typedef _Float16 h8 __attribute__((ext_vector_type(8)));
typedef float f4 __attribute__((ext_vector_type(4)));

#define MFMA32(A, B, C) __builtin_amdgcn_mfma_f32_16x16x32_f16((A), (B), (C), 0, 0, 0)
#define SB() __builtin_amdgcn_sched_barrier(0)

__device__ __forceinline__ h8 cat(h4 a, h4 b) {
  return __builtin_shufflevector(a, b, 0, 1, 2, 3, 4, 5, 6, 7);
}

__device__ __forceinline__ float fast_tanh(float x) {
  float e = __expf(2.0f * x);
  return 1.0f - 2.0f * __builtin_amdgcn_rcpf(e + 1.0f);
}

// ---------------- prepack: global weights -> MFMA fragment order in ws ----
// slot->k map (lane group g=lane>>4, elem j): j<4 -> g*4+j ; j>=4 -> 16+g*4+j-4
// ws layout (bytes):
//   [0      .. 8192 )  w0: 8 fblocks x 64 lanes x h8          (8 KB)
//   [8192   .. 40960)  w1: 8 fblocks x 4 chunks x 64 x h8     (32 KB)
//   [40960  .. 49152)  w2: 2 fblocks x 4 chunks x 64 x h8     (8 KB)
//   [49152  .. 51456)  bias/time-row floats: bw[576]
//       bw[0:128]=b0  bw[128:256]=W0row32  bw[256:384]=b1 bw[384:512]=W1row128
//       bw[512:544]=b2 bw[544:576]=W2row128
__global__ void prepack_kernel(const float* __restrict__ W0, const float* __restrict__ b0,
                               const float* __restrict__ W1, const float* __restrict__ b1,
                               const float* __restrict__ W2, const float* __restrict__ b2,
                               char* __restrict__ ws) {
  h8* w0f = (h8*)(ws);
  h8* w1f = (h8*)(ws + 8192);
  h8* w2f = (h8*)(ws + 40960);
  float* bw = (float*)(ws + 49152);
  int tid = blockIdx.x * blockDim.x + threadIdx.x;
  int np = gridDim.x * blockDim.x;
  for (int e = tid; e < 512; e += np) {  // w0: K=32 covers the whole input
    int fb = e >> 6, lane = e & 63;
    int g = lane >> 4, m = (fb << 4) + (lane & 15);
    h8 v;
#pragma unroll
    for (int j = 0; j < 8; j++) {
      int kl = (j < 4) ? (g * 4 + j) : (16 + g * 4 + j - 4);
      v[j] = (_Float16)W0[kl * 128 + m];
    }
    w0f[e] = v;
  }
  for (int e = tid; e < 2048; e += np) {  // w1: 4 chunks of K=32
    int fb = e >> 8, c = (e >> 6) & 3, lane = e & 63;
    int g = lane >> 4, m = (fb << 4) + (lane & 15);
    h8 v;
#pragma unroll
    for (int j = 0; j < 8; j++) {
      int kl = (j < 4) ? (g * 4 + j) : (16 + g * 4 + j - 4);
      v[j] = (_Float16)W1[(c * 32 + kl) * 128 + m];
    }
    w1f[e] = v;
  }
  for (int e = tid; e < 512; e += np) {  // w2: 2 fblocks x 4 chunks
    int fb = e >> 8, c = (e >> 6) & 3, lane = e & 63;
    int g = lane >> 4, m = (fb << 4) + (lane & 15);
    h8 v;
#pragma unroll
    for (int j = 0; j < 8; j++) {
      int kl = (j < 4) ? (g * 4 + j) : (16 + g * 4 + j - 4);
      v[j] = (_Float16)W2[(c * 32 + kl) * 32 + m];
    }
    w2f[e] = v;
  }
  for (int e = tid; e < 128; e += np) {
    bw[e] = b0[e];
    bw[128 + e] = W0[32 * 128 + e];
    bw[256 + e] = b1[e];
    bw[384 + e] = W1[128 * 128 + e];
  }
  for (int e = tid; e < 32; e += np) {
    bw[512 + e] = b2[e];
    bw[544 + e] = W2[128 * 32 + e];
  }
}

// ---- per-layer macros: all state in NAMED registers, offsets constant ----
#define TANHPACK(ap, at, HH, HD)                                              \
  {                                                                           \
    float th0 = fast_tanh((ap).x), th1 = fast_tanh((ap).y);                   \
    float th2 = fast_tanh((ap).z), th3 = fast_tanh((ap).w);                   \
    HH = (h4){(_Float16)th0, (_Float16)th1, (_Float16)th2, (_Float16)th3};    \
    HD = (h4){(_Float16)((1.0f - th0 * th0) * (at).x),                        \
              (_Float16)((1.0f - th1 * th1) * (at).y),                        \
              (_Float16)((1.0f - th2 * th2) * (at).z),                        \
              (_Float16)((1.0f - th3 * th3) * (at).w)};                       \
  }

#define L1(F, HH, HD)                                                         \
  {                                                                           \
    f4 bb = *(const f4*)&s_bw[(F) * 16 + g4];                                 \
    f4 bt = *(const f4*)&s_bw[128 + (F) * 16 + g4];                           \
    f4 ap = bb + t * bt;                                                      \
    f4 at = {0.0f, 0.0f, 0.0f, 0.0f};                                         \
    h8 A = s_w0[(F) * 64 + lane];                                             \
    ap = MFMA32(A, hz8, ap);                                                  \
    at = MFMA32(A, hE8, at);                                                  \
    TANHPACK(ap, at, HH, HD)                                                  \
  }                                                                           \
  SB();

#define L2T(F, C, BH, BD)                                                     \
  {                                                                           \
    h8 A = s_w1[((F) * 4 + (C)) * 64 + lane];                                 \
    ap = MFMA32(A, BH, ap);                                                   \
    at = MFMA32(A, BD, at);                                                   \
  }

#define L2(F, GG, GD)                                                         \
  {                                                                           \
    f4 bb = *(const f4*)&s_bw[256 + (F) * 16 + g4];                           \
    f4 bt = *(const f4*)&s_bw[384 + (F) * 16 + g4];                           \
    f4 ap = bb + t * bt;                                                      \
    f4 at = {0.0f, 0.0f, 0.0f, 0.0f};                                         \
    L2T(F, 0, hp0, dp0) L2T(F, 1, hp1, dp1)                                   \
    L2T(F, 2, hp2, dp2) L2T(F, 3, hp3, dp3)                                   \
    TANHPACK(ap, at, GG, GD)                                                  \
  }                                                                           \
  SB();

#define L3T(F, C, BH, BD)                                                     \
  {                                                                           \
    h8 A = s_w2[((F) * 4 + (C)) * 64 + lane];                                 \
    ap = MFMA32(A, BH, ap);                                                   \
    at = MFMA32(A, BD, at);                                                   \
  }

#define L3(F, KC, EH)                                                         \
  {                                                                           \
    f4 bb = *(const f4*)&s_bw[512 + (F) * 16 + g4];                           \
    f4 bt = *(const f4*)&s_bw[544 + (F) * 16 + g4];                           \
    f4 ap = bb + t * bt;                                                      \
    f4 at = {0.0f, 0.0f, 0.0f, 0.0f};                                         \
    L3T(F, 0, gp0, ep0) L3T(F, 1, gp1, ep1)                                   \
    L3T(F, 2, gp2, ep2) L3T(F, 3, gp3, ep3)                                   \
    KC = ap;                                                                  \
    lp += (EH).x * at.x + (EH).y * at.y + (EH).z * at.z + (EH).w * at.w;      \
  }                                                                           \
  SB();

// ---------------- main kernel: 16 samples/wave, 4 waves/block --------------
__global__ __launch_bounds__(256, 2) void ffjord_kernel(
    const float* __restrict__ z1g, const float* __restrict__ epsg,
    const char* __restrict__ ws, float* __restrict__ out) {
  __shared__ h8 s_w0[512];    // 8 KB
  __shared__ h8 s_w1[2048];   // 32 KB
  __shared__ h8 s_w2[512];    // 8 KB
  __shared__ float s_bw[576]; // 2.25 KB

  {
    int tt = threadIdx.x;
    const f4* s0 = (const f4*)(ws);
    const f4* s1 = (const f4*)(ws + 8192);
    const f4* s2 = (const f4*)(ws + 40960);
    const f4* s3 = (const f4*)(ws + 49152);
    f4* d0 = (f4*)s_w0;
    f4* d1 = (f4*)s_w1;
    f4* d2 = (f4*)s_w2;
    f4* d3 = (f4*)s_bw;
#pragma unroll
    for (int i = 0; i < 2; i++) d0[tt + 256 * i] = s0[tt + 256 * i];
#pragma unroll
    for (int i = 0; i < 8; i++) d1[tt + 256 * i] = s1[tt + 256 * i];
#pragma unroll
    for (int i = 0; i < 2; i++) d2[tt + 256 * i] = s2[tt + 256 * i];
    if (tt < 144) d3[tt] = s3[tt];
  }
  __syncthreads();

  const int lane = threadIdx.x & 63;
  const int wv = threadIdx.x >> 6;
  const int sl = lane & 15;
  const int g4 = ((lane >> 4) << 2);
  const int sample = (blockIdx.x * 4 + wv) * 16 + sl;

  // per-lane state: features {c*16 + g4 + j}, c in {0,1}, j in 0..3
  f4 za, zb, ea, eb;
  {
    const f4* zp = (const f4*)(z1g + sample * 32);
    za = zp[g4 >> 2];
    zb = zp[(16 + g4) >> 2];
    const f4* ep = (const f4*)(epsg + sample * 32);
    ea = ep[g4 >> 2];
    eb = ep[(16 + g4) >> 2];
  }
  const h8 hE8 = cat((h4){(_Float16)ea.x, (_Float16)ea.y, (_Float16)ea.z, (_Float16)ea.w},
                     (h4){(_Float16)eb.x, (_Float16)eb.y, (_Float16)eb.z, (_Float16)eb.w});

  float ld = 0.0f;

  // RK4, reversed time: 5 steps, dt = -0.2
#pragma unroll 1
  for (int step = 0; step < 5; step++) {
    float t1 = 1.0f - 0.2f * (float)step;
    f4 kca = {0.0f, 0.0f, 0.0f, 0.0f}, kcb = {0.0f, 0.0f, 0.0f, 0.0f};
    f4 dka = {0.0f, 0.0f, 0.0f, 0.0f}, dkb = {0.0f, 0.0f, 0.0f, 0.0f};
    float dl = 0.0f;
#pragma unroll 1
    for (int st = 0; st < 4; st++) {
      // stage input scale == stage t offset: {0, -0.1, -0.1, -0.2}
      float isc = (st == 0) ? 0.0f : ((st == 3) ? -0.2f : -0.1f);
      float wg = (st == 1 || st == 2) ? 2.0f : 1.0f;
      float t = t1 + isc;
      h8 hz8 = cat(
          (h4){(_Float16)(za.x + isc * kca.x), (_Float16)(za.y + isc * kca.y),
               (_Float16)(za.z + isc * kca.z), (_Float16)(za.w + isc * kca.w)},
          (h4){(_Float16)(zb.x + isc * kcb.x), (_Float16)(zb.y + isc * kcb.y),
               (_Float16)(zb.z + isc * kcb.z), (_Float16)(zb.w + isc * kcb.w)});
      SB();

      // layer 1 (32 -> 128, tanh), primal + tangent
      h4 hh0, hh1, hh2, hh3, hh4, hh5, hh6, hh7;
      h4 hd0, hd1, hd2, hd3, hd4, hd5, hd6, hd7;
      L1(0, hh0, hd0) L1(1, hh1, hd1) L1(2, hh2, hd2) L1(3, hh3, hd3)
      L1(4, hh4, hd4) L1(5, hh5, hd5) L1(6, hh6, hd6) L1(7, hh7, hd7)

      // pair K=16 fragments into K=32 B operands
      h8 hp0 = cat(hh0, hh1), hp1 = cat(hh2, hh3), hp2 = cat(hh4, hh5), hp3 = cat(hh6, hh7);
      h8 dp0 = cat(hd0, hd1), dp1 = cat(hd2, hd3), dp2 = cat(hd4, hd5), dp3 = cat(hd6, hd7);

      // layer 2 (128 -> 128, tanh)
      h4 g10, g11, g12, g13, g14, g15, g16, g17;
      h4 gd0, gd1, gd2, gd3, gd4, gd5, gd6, gd7;
      L2(0, g10, gd0) L2(1, g11, gd1) L2(2, g12, gd2) L2(3, g13, gd3)
      L2(4, g14, gd4) L2(5, g15, gd5) L2(6, g16, gd6) L2(7, g17, gd7)

      h8 gp0 = cat(g10, g11), gp1 = cat(g12, g13), gp2 = cat(g14, g15), gp3 = cat(g16, g17);
      h8 ep0 = cat(gd0, gd1), ep1 = cat(gd2, gd3), ep2 = cat(gd4, gd5), ep3 = cat(gd6, gd7);

      // layer 3 (128 -> 32, linear) + Hutchinson partial
      float lp = 0.0f;
      L3(0, kca, ea)
      L3(1, kcb, eb)
      lp += __shfl_xor(lp, 16, 64);
      lp += __shfl_xor(lp, 32, 64);

      dka += wg * kca;
      dkb += wg * kcb;
      dl += wg * lp;
    }
    za += (-0.2f / 6.0f) * dka;
    zb += (-0.2f / 6.0f) * dkb;
    ld += (0.2f / 6.0f) * dl;   // ld -= dlogpz, dlogpz = dl*(dt/6), dt=-0.2
  }

  {
    f4* op = (f4*)(out + sample * 32);
    op[g4 >> 2] = za;
    op[(16 + g4) >> 2] = zb;
    if (lane < 16) out[131072 * 32 + sample] = ld;
  }
}

extern "C" void kernel_launch(void* const* d_in, const int* in_sizes, int n_in,
                              void* d_out, int out_size, void* d_ws, size_t ws_size,
                              hipStream_t stream) {
  (void)in_sizes; (void)n_in; (void)out_size; (void)ws_size;
  const float* z1 = (const float*)d_in[0];
  const float* eps = (const float*)d_in[1];
  const float* W0 = (const float*)d_in[2];
  const float* b0 = (const float*)d_in[3];
  const float* W1 = (const float*)d_in[4];
  const float* b1 = (const float*)d_in[5];
  const float* W2 = (const float*)d_in[6];
  const float* b2 = (const float*)d_in[7];
  float* out = (float*)d_out;

  prepack_kernel<<<16, 256, 0, stream>>>(W0, b0, W1, b1, W2, b2, (char*)d_ws);
  ffjord_kernel<<<131072 / 64, 256, 0, stream>>>(z1, eps, (const char*)d_ws, out);
}

// Round 11
// 301.022 us; speedup vs baseline: 1.3729x; 1.1040x over previous
//
#include <hip/hip_runtime.h>

// FFJORD CNF on MI355X. Transposed-MFMA design, K=32 native shape.
// R9: LDS-read + VALU co-bound per R8 counters (84 ds_read_b128/eval ~269us
// of LDS pipe time; VALU ~250us; MFMA only 120us). This round:
//  - w0/w2 A-fragments register-resident (16 x h8 = 64 VGPR, loaded once
//    from global) -> L1/L3 LDS A-reads gone.
//  - bias+time rows precomputed per distinct t (11 values) in prepack:
//    beff[11][288] f32 -> ONE f4 LDS read replaces 2 reads + 4 fma.
//  - TANHPACK: cvt_pkrtz packed converts (bit_cast to _Float16 vec - the
//    builtin returns __fp16 vec, R9 compile fail) + packed-f16 derivative.
// LDS: s_w1 32KB + s_be 12.4KB = 45.4KB -> 3 blocks/CU.

typedef _Float16 h2 __attribute__((ext_vector_type(2)));
typedef _Float16 h4 __attribute__((ext_vector_type(4)));
typedef _Float16 h8 __attribute__((ext_vector_type(8)));
typedef float f4 __attribute__((ext_vector_type(4)));

#define MFMA32(A, B, C) __builtin_amdgcn_mfma_f32_16x16x32_f16((A), (B), (C), 0, 0, 0)
#define SB() __builtin_amdgcn_sched_barrier(0)

__device__ __forceinline__ h8 cat(h4 a, h4 b) {
  return __builtin_shufflevector(a, b, 0, 1, 2, 3, 4, 5, 6, 7);
}

__device__ __forceinline__ h2 pkrtz(float a, float b) {
  return __builtin_bit_cast(h2, __builtin_amdgcn_cvt_pkrtz(a, b));
}

__device__ __forceinline__ float fast_tanh(float x) {
  float e = __expf(2.0f * x);
  return 1.0f - 2.0f * __builtin_amdgcn_rcpf(e + 1.0f);
}

// ---------------- prepack: global weights -> MFMA fragment order in ws ----
// slot->k map (lane group g=lane>>4, elem j): j<4 -> g*4+j ; j>=4 -> 16+g*4+j-4
// ws layout (bytes):
//   [0      .. 8192 )  w0: 8 fblocks x 64 lanes x h8          (8 KB)
//   [8192   .. 40960)  w1: 8 fblocks x 4 chunks x 64 x h8     (32 KB)
//   [40960  .. 49152)  w2: 2 fblocks x 4 chunks x 64 x h8     (8 KB)
//   [49152  .. 61824)  beff[11][288] f32: per t in {0.0..1.0 step 0.1}:
//       [0:128]=b0+t*W0row  [128:256]=b1+t*W1row  [256:288]=b2+t*W2row
__global__ void prepack_kernel(const float* __restrict__ W0, const float* __restrict__ b0,
                               const float* __restrict__ W1, const float* __restrict__ b1,
                               const float* __restrict__ W2, const float* __restrict__ b2,
                               char* __restrict__ ws) {
  h8* w0f = (h8*)(ws);
  h8* w1f = (h8*)(ws + 8192);
  h8* w2f = (h8*)(ws + 40960);
  float* be = (float*)(ws + 49152);
  int tid = blockIdx.x * blockDim.x + threadIdx.x;
  int np = gridDim.x * blockDim.x;
  for (int e = tid; e < 512; e += np) {  // w0: K=32 covers the whole input
    int fb = e >> 6, lane = e & 63;
    int g = lane >> 4, m = (fb << 4) + (lane & 15);
    h8 v;
#pragma unroll
    for (int j = 0; j < 8; j++) {
      int kl = (j < 4) ? (g * 4 + j) : (16 + g * 4 + j - 4);
      v[j] = (_Float16)W0[kl * 128 + m];
    }
    w0f[e] = v;
  }
  for (int e = tid; e < 2048; e += np) {  // w1: 4 chunks of K=32
    int fb = e >> 8, c = (e >> 6) & 3, lane = e & 63;
    int g = lane >> 4, m = (fb << 4) + (lane & 15);
    h8 v;
#pragma unroll
    for (int j = 0; j < 8; j++) {
      int kl = (j < 4) ? (g * 4 + j) : (16 + g * 4 + j - 4);
      v[j] = (_Float16)W1[(c * 32 + kl) * 128 + m];
    }
    w1f[e] = v;
  }
  for (int e = tid; e < 512; e += np) {  // w2: 2 fblocks x 4 chunks
    int fb = e >> 8, c = (e >> 6) & 3, lane = e & 63;
    int g = lane >> 4, m = (fb << 4) + (lane & 15);
    h8 v;
#pragma unroll
    for (int j = 0; j < 8; j++) {
      int kl = (j < 4) ? (g * 4 + j) : (16 + g * 4 + j - 4);
      v[j] = (_Float16)W2[(c * 32 + kl) * 32 + m];
    }
    w2f[e] = v;
  }
  for (int e = tid; e < 11 * 288; e += np) {
    int ti = e / 288, off = e - ti * 288;
    float tv = 0.1f * (float)ti;
    float v;
    if (off < 128) v = b0[off] + tv * W0[32 * 128 + off];
    else if (off < 256) { int f = off - 128; v = b1[f] + tv * W1[128 * 128 + f]; }
    else { int f = off - 256; v = b2[f] + tv * W2[128 * 32 + f]; }
    be[e] = v;
  }
}

// ---- per-layer macros: all state in NAMED registers, offsets constant ----
#define TANHPACK(ap, at, HH, HD)                                              \
  {                                                                           \
    float th0 = fast_tanh((ap).x), th1 = fast_tanh((ap).y);                   \
    float th2 = fast_tanh((ap).z), th3 = fast_tanh((ap).w);                   \
    h2 hlo = pkrtz(th0, th1);                                                 \
    h2 hhi = pkrtz(th2, th3);                                                 \
    HH = __builtin_shufflevector(hlo, hhi, 0, 1, 2, 3);                       \
    h2 alo = pkrtz((at).x, (at).y);                                           \
    h2 ahi = pkrtz((at).z, (at).w);                                           \
    h4 at4 = __builtin_shufflevector(alo, ahi, 0, 1, 2, 3);                   \
    h4 d4 = hone - HH * HH;                                                   \
    HD = d4 * at4;                                                            \
  }

#define L1(F, HH, HD)                                                         \
  {                                                                           \
    f4 ap = *(const f4*)&s_be[tbase + (F) * 16 + g4];                         \
    f4 at = {0.0f, 0.0f, 0.0f, 0.0f};                                         \
    ap = MFMA32(w0r##F, hz8, ap);                                             \
    at = MFMA32(w0r##F, hE8, at);                                             \
    TANHPACK(ap, at, HH, HD)                                                  \
  }                                                                           \
  SB();

#define L2T(F, C, BH, BD)                                                     \
  {                                                                           \
    h8 A = s_w1[((F) * 4 + (C)) * 64 + lane];                                 \
    ap = MFMA32(A, BH, ap);                                                   \
    at = MFMA32(A, BD, at);                                                   \
  }

#define L2(F, GG, GD)                                                         \
  {                                                                           \
    f4 ap = *(const f4*)&s_be[tbase + 128 + (F) * 16 + g4];                   \
    f4 at = {0.0f, 0.0f, 0.0f, 0.0f};                                         \
    L2T(F, 0, hp0, dp0) L2T(F, 1, hp1, dp1)                                   \
    L2T(F, 2, hp2, dp2) L2T(F, 3, hp3, dp3)                                   \
    TANHPACK(ap, at, GG, GD)                                                  \
  }                                                                           \
  SB();

#define L3(F, A0, A1, A2, A3, KC, EH)                                         \
  {                                                                           \
    f4 ap = *(const f4*)&s_be[tbase + 256 + (F) * 16 + g4];                   \
    f4 at = {0.0f, 0.0f, 0.0f, 0.0f};                                         \
    ap = MFMA32(A0, gp0, ap); at = MFMA32(A0, ep0, at);                       \
    ap = MFMA32(A1, gp1, ap); at = MFMA32(A1, ep1, at);                       \
    ap = MFMA32(A2, gp2, ap); at = MFMA32(A2, ep2, at);                       \
    ap = MFMA32(A3, gp3, ap); at = MFMA32(A3, ep3, at);                       \
    KC = ap;                                                                  \
    lp += (EH).x * at.x + (EH).y * at.y + (EH).z * at.z + (EH).w * at.w;      \
  }                                                                           \
  SB();

// ---------------- main kernel: 16 samples/wave, 4 waves/block --------------
__global__ __launch_bounds__(256, 2) void ffjord_kernel(
    const float* __restrict__ z1g, const float* __restrict__ epsg,
    const char* __restrict__ ws, float* __restrict__ out) {
  __shared__ h8 s_w1[2048];    // 32 KB
  __shared__ float s_be[3168]; // 12.375 KB

  {
    int tt = threadIdx.x;
    const f4* s1 = (const f4*)(ws + 8192);
    f4* d1 = (f4*)s_w1;
#pragma unroll
    for (int i = 0; i < 8; i++) d1[tt + 256 * i] = s1[tt + 256 * i];
    const f4* s3 = (const f4*)(ws + 49152);
    f4* d3 = (f4*)s_be;
#pragma unroll
    for (int i = 0; i < 4; i++) {
      int idx = tt + 256 * i;
      if (idx < 792) d3[idx] = s3[idx];
    }
  }
  __syncthreads();

  const int lane = threadIdx.x & 63;
  const int wv = threadIdx.x >> 6;
  const int sl = lane & 15;
  const int g4 = ((lane >> 4) << 2);
  const int sample = (blockIdx.x * 4 + wv) * 16 + sl;
  const h4 hone = {(_Float16)1.0f, (_Float16)1.0f, (_Float16)1.0f, (_Float16)1.0f};

  // register-resident w0/w2 A-fragments (loaded once, coalesced)
  const h8* w0g = (const h8*)(ws);
  const h8* w2g = (const h8*)(ws + 40960);
  const h8 w0r0 = w0g[0 * 64 + lane], w0r1 = w0g[1 * 64 + lane];
  const h8 w0r2 = w0g[2 * 64 + lane], w0r3 = w0g[3 * 64 + lane];
  const h8 w0r4 = w0g[4 * 64 + lane], w0r5 = w0g[5 * 64 + lane];
  const h8 w0r6 = w0g[6 * 64 + lane], w0r7 = w0g[7 * 64 + lane];
  const h8 w2r0 = w2g[0 * 64 + lane], w2r1 = w2g[1 * 64 + lane];
  const h8 w2r2 = w2g[2 * 64 + lane], w2r3 = w2g[3 * 64 + lane];
  const h8 w2r4 = w2g[4 * 64 + lane], w2r5 = w2g[5 * 64 + lane];
  const h8 w2r6 = w2g[6 * 64 + lane], w2r7 = w2g[7 * 64 + lane];

  // per-lane state: features {c*16 + g4 + j}, c in {0,1}, j in 0..3
  f4 za, zb, ea, eb;
  {
    const f4* zp = (const f4*)(z1g + sample * 32);
    za = zp[g4 >> 2];
    zb = zp[(16 + g4) >> 2];
    const f4* ep = (const f4*)(epsg + sample * 32);
    ea = ep[g4 >> 2];
    eb = ep[(16 + g4) >> 2];
  }
  const h8 hE8 = cat((h4){(_Float16)ea.x, (_Float16)ea.y, (_Float16)ea.z, (_Float16)ea.w},
                     (h4){(_Float16)eb.x, (_Float16)eb.y, (_Float16)eb.z, (_Float16)eb.w});

  float ld = 0.0f;

  // RK4, reversed time: 5 steps, dt = -0.2
#pragma unroll 1
  for (int step = 0; step < 5; step++) {
    f4 kca = {0.0f, 0.0f, 0.0f, 0.0f}, kcb = {0.0f, 0.0f, 0.0f, 0.0f};
    f4 dka = {0.0f, 0.0f, 0.0f, 0.0f}, dkb = {0.0f, 0.0f, 0.0f, 0.0f};
    float dl = 0.0f;
#pragma unroll 1
    for (int st = 0; st < 4; st++) {
      // stage input scale == stage t offset: {0, -0.1, -0.1, -0.2}
      float isc = (st == 0) ? 0.0f : ((st == 3) ? -0.2f : -0.1f);
      float wg = (st == 1 || st == 2) ? 2.0f : 1.0f;
      int dst = (st == 0) ? 0 : ((st == 3) ? 2 : 1);
      int tbase = (10 - 2 * step - dst) * 288;  // t = (tbase/288) * 0.1
      h8 hz8 = cat(
          (h4){(_Float16)(za.x + isc * kca.x), (_Float16)(za.y + isc * kca.y),
               (_Float16)(za.z + isc * kca.z), (_Float16)(za.w + isc * kca.w)},
          (h4){(_Float16)(zb.x + isc * kcb.x), (_Float16)(zb.y + isc * kcb.y),
               (_Float16)(zb.z + isc * kcb.z), (_Float16)(zb.w + isc * kcb.w)});
      SB();

      // layer 1 (32 -> 128, tanh), primal + tangent
      h4 hh0, hh1, hh2, hh3, hh4, hh5, hh6, hh7;
      h4 hd0, hd1, hd2, hd3, hd4, hd5, hd6, hd7;
      L1(0, hh0, hd0) L1(1, hh1, hd1) L1(2, hh2, hd2) L1(3, hh3, hd3)
      L1(4, hh4, hd4) L1(5, hh5, hd5) L1(6, hh6, hd6) L1(7, hh7, hd7)

      // pair K=16 fragments into K=32 B operands
      h8 hp0 = cat(hh0, hh1), hp1 = cat(hh2, hh3), hp2 = cat(hh4, hh5), hp3 = cat(hh6, hh7);
      h8 dp0 = cat(hd0, hd1), dp1 = cat(hd2, hd3), dp2 = cat(hd4, hd5), dp3 = cat(hd6, hd7);

      // layer 2 (128 -> 128, tanh)
      h4 g10, g11, g12, g13, g14, g15, g16, g17;
      h4 gd0, gd1, gd2, gd3, gd4, gd5, gd6, gd7;
      L2(0, g10, gd0) L2(1, g11, gd1) L2(2, g12, gd2) L2(3, g13, gd3)
      L2(4, g14, gd4) L2(5, g15, gd5) L2(6, g16, gd6) L2(7, g17, gd7)

      h8 gp0 = cat(g10, g11), gp1 = cat(g12, g13), gp2 = cat(g14, g15), gp3 = cat(g16, g17);
      h8 ep0 = cat(gd0, gd1), ep1 = cat(gd2, gd3), ep2 = cat(gd4, gd5), ep3 = cat(gd6, gd7);

      // layer 3 (128 -> 32, linear) + Hutchinson partial
      float lp = 0.0f;
      L3(0, w2r0, w2r1, w2r2, w2r3, kca, ea)
      L3(1, w2r4, w2r5, w2r6, w2r7, kcb, eb)
      lp += __shfl_xor(lp, 16, 64);
      lp += __shfl_xor(lp, 32, 64);

      dka += wg * kca;
      dkb += wg * kcb;
      dl += wg * lp;
    }
    za += (-0.2f / 6.0f) * dka;
    zb += (-0.2f / 6.0f) * dkb;
    ld += (0.2f / 6.0f) * dl;   // ld -= dlogpz, dlogpz = dl*(dt/6), dt=-0.2
  }

  {
    f4* op = (f4*)(out + sample * 32);
    op[g4 >> 2] = za;
    op[(16 + g4) >> 2] = zb;
    if (lane < 16) out[131072 * 32 + sample] = ld;
  }
}

extern "C" void kernel_launch(void* const* d_in, const int* in_sizes, int n_in,
                              void* d_out, int out_size, void* d_ws, size_t ws_size,
                              hipStream_t stream) {
  (void)in_sizes; (void)n_in; (void)out_size; (void)ws_size;
  const float* z1 = (const float*)d_in[0];
  const float* eps = (const float*)d_in[1];
  const float* W0 = (const float*)d_in[2];
  const float* b0 = (const float*)d_in[3];
  const float* W1 = (const float*)d_in[4];
  const float* b1 = (const float*)d_in[5];
  const float* W2 = (const float*)d_in[6];
  const float* b2 = (const float*)d_in[7];
  float* out = (float*)d_out;

  prepack_kernel<<<16, 256, 0, stream>>>(W0, b0, W1, b1, W2, b2, (char*)d_ws);
  ffjord_kernel<<<131072 / 64, 256, 0, stream>>>(z1, eps, (const char*)d_ws, out);
}